// Round 5
// baseline (251.192 us; speedup 1.0000x reference)
//
#include <hip/hip_runtime.h>

// CAPBlock r5: occupancy fix (q in LDS, launch_bounds(256,4)), global_load_lds
// staging with pre-swizzled sources, 64x64-tile fp16 GEMMs (2048 blocks).
// Shapes: B=4, Q=256, K=4096, Ein=E=512, H=8, DH=64.
//
// ws (52.43MB, same as r4):
//   mflag 16B | qh 1MB | kh 16.8MB | vT 16.8MB | REGION 17.8MB
//   REGION phase1: bag_h 16.8 | wqk_h 0.5 | wv_h 0.5   (convert -> GEMMs)
//   REGION phase2: po 16.8 | ps 0.5                     (attn -> combine)

#define BATCH 4
#define QLEN 256
#define KLEN 4096
#define EDIM 512
#define NHEAD 8
#define DHEAD 64
#define NC 16

// alpha = log2(e)/L1_SCALING ; C2 = L1_CENTER*alpha  (k,q prescaled by alpha)
#define ALPHA 0.21153831f
#define C2EXP 15.276518f

typedef float f32x4 __attribute__((ext_vector_type(4)));
typedef _Float16 f16x8 __attribute__((ext_vector_type(8)));
typedef _Float16 f16x4 __attribute__((ext_vector_type(4)));
typedef _Float16 h2 __attribute__((ext_vector_type(2)));
typedef unsigned int u32x4 __attribute__((ext_vector_type(4)));

// async global->LDS 16B: dest = uniform base + lane*16; source per-lane.
#define GLDS16(g, l)                                                     \
    __builtin_amdgcn_global_load_lds(                                    \
        (const __attribute__((address_space(1))) unsigned int*)(g),      \
        (__attribute__((address_space(3))) unsigned int*)(l), 16, 0, 0)

// ---------------- mask dtype detection (bool-as-byte vs int32) --------------
__global__ void detect_mask_kernel(const unsigned char* __restrict__ m,
                                   int* __restrict__ flag) {
    __shared__ int nz;
    if (threadIdx.x == 0) nz = 0;
    __syncthreads();
    int acc = 0;
    for (int i = threadIdx.x; i < BATCH * KLEN; i += 256)
        if (i & 3) acc |= m[i];
    if (acc) atomicOr(&nz, 1);
    __syncthreads();
    if (threadIdx.x == 0) *flag = (nz == 0) ? 1 : 0;  // 1 => int32, 0 => byte
}

// ---------------- f32 -> fp16 convert (bag, Wqk, Wv) ------------------------
__global__ __launch_bounds__(256) void convert_kernel(
    const float* __restrict__ bag, const float* __restrict__ wqk,
    const float* __restrict__ wv, _Float16* __restrict__ bag_h,
    _Float16* __restrict__ wqk_h, _Float16* __restrict__ wv_h) {
    const int NB = (BATCH * KLEN * EDIM) / 4;  // float4 counts
    const int NW = (EDIM * EDIM) / 4;
    for (int i = blockIdx.x * 256 + threadIdx.x; i < NB + 2 * NW;
         i += gridDim.x * 256) {
        const float4* s;
        _Float16* d;
        int j;
        if (i < NB) { s = (const float4*)bag; d = bag_h; j = i; }
        else if (i < NB + NW) { s = (const float4*)wqk; d = wqk_h; j = i - NB; }
        else { s = (const float4*)wv; d = wv_h; j = i - NB - NW; }
        const float4 v = s[j];
        f16x4 h;
        h[0] = (_Float16)v.x; h[1] = (_Float16)v.y;
        h[2] = (_Float16)v.z; h[3] = (_Float16)v.w;
        *(f16x4*)&d[(size_t)j * 4] = h;
    }
}

// ---------------- pure-fp16 NT MFMA GEMM, 64x64 tile ------------------------
// C[m][n] = sum_k A[m][k]*W[n][k]; BK=64, 4 waves (2x2), wave = 32x32 (2x2
// frags of 16x16x32). glds staging, LDS unit-XOR swizzle u^(row&7) so frag
// reads spread all 8 16B-unit positions (b128 data-minimum, no extra conflict).
// OUTM=0: fp16 row-major, (acc+bias[n])*scale[n]*smul.
// OUTM=1: vT[(b*8+h)*64+d][k] fp16, acc+bias[n].
template <int OUTM>
__global__ __launch_bounds__(256) void gemm_h16_mfma(
    const _Float16* __restrict__ A, const _Float16* __restrict__ W,
    const float* __restrict__ bias, const float* __restrict__ scale,
    float smul, _Float16* __restrict__ C) {
    __shared__ _Float16 Ah[64][64];
    __shared__ _Float16 Bh[64][64];

    const int tid = threadIdx.x;
    const int lane = tid & 63, wid = tid >> 6;
    const int wm = wid >> 1, wn = wid & 1;
    const int l15 = lane & 15, kg4 = lane >> 4;
    const int row8 = lane >> 3, u = lane & 7;
    const int n0 = blockIdx.x * 64, m0 = blockIdx.y * 64;

    f32x4 acc[2][2];
#pragma unroll
    for (int i = 0; i < 2; ++i)
#pragma unroll
        for (int j = 0; j < 2; ++j) acc[i][j] = (f32x4)0.f;

    for (int k0 = 0; k0 < EDIM; k0 += 64) {
        __syncthreads();  // previous tile consumed
#pragma unroll
        for (int i = 0; i < 2; ++i) {
            const int rr = wid * 16 + i * 8 + row8;      // lane's dest row
            const int uo = (u ^ row8) * 8;               // pre-swizzled source
            GLDS16(&A[(size_t)(m0 + rr) * EDIM + k0 + uo], &Ah[wid * 16 + i * 8][0]);
            GLDS16(&W[(size_t)(n0 + rr) * EDIM + k0 + uo], &Bh[wid * 16 + i * 8][0]);
        }
        __syncthreads();

#pragma unroll
        for (int s = 0; s < 2; ++s) {
            f16x8 a8[2], b8[2];
#pragma unroll
            for (int mf = 0; mf < 2; ++mf) {
                const int row = wm * 32 + mf * 16 + l15;
                a8[mf] = *(const f16x8*)&Ah[row][(((s * 4 + kg4) ^ (l15 & 7))) * 8];
            }
#pragma unroll
            for (int nf = 0; nf < 2; ++nf) {
                const int row = wn * 32 + nf * 16 + l15;
                b8[nf] = *(const f16x8*)&Bh[row][(((s * 4 + kg4) ^ (l15 & 7))) * 8];
            }
#pragma unroll
            for (int nf = 0; nf < 2; ++nf)
#pragma unroll
                for (int mf = 0; mf < 2; ++mf)
                    acc[mf][nf] = __builtin_amdgcn_mfma_f32_16x16x32_f16(
                        a8[mf], b8[nf], acc[mf][nf], 0, 0, 0);
        }
    }

#pragma unroll
    for (int nf = 0; nf < 2; ++nf) {
        const int n = n0 + wn * 32 + nf * 16 + l15;
        const float bi = bias[n];
        if constexpr (OUTM == 0) {
            const float sc = (scale ? scale[n] : 1.f) * smul;
#pragma unroll
            for (int mf = 0; mf < 2; ++mf)
#pragma unroll
                for (int rr = 0; rr < 4; ++rr) {
                    const int m = m0 + wm * 32 + mf * 16 + kg4 * 4 + rr;
                    C[(size_t)m * EDIM + n] = (_Float16)((acc[mf][nf][rr] + bi) * sc);
                }
        } else {
#pragma unroll
            for (int mf = 0; mf < 2; ++mf) {
                const int kb = m0 + wm * 32 + mf * 16 + kg4 * 4;  // global m
                const int bb = kb >> 12, kk = kb & (KLEN - 1);    // batch, k
                f16x4 pk;
#pragma unroll
                for (int rr = 0; rr < 4; ++rr) pk[rr] = (_Float16)(acc[mf][nf][rr] + bi);
                *(f16x4*)&C[((size_t)(bb * NHEAD + (n >> 6)) * DHEAD + (n & 63)) * KLEN + kk] = pk;
            }
        }
    }
}

// ---------------- mixed f32->fp16 MFMA GEMM (query projection, small) -------
__global__ __launch_bounds__(256) void gemm_f16_mfma(
    const float* __restrict__ A, const float* __restrict__ W,
    const float* __restrict__ bias, const float* __restrict__ scale,
    float smul, _Float16* __restrict__ C) {
    __shared__ _Float16 As[128][40];
    __shared__ _Float16 Bs[128][40];

    const int tid = threadIdx.x;
    const int lane = tid & 63, wid = tid >> 6;
    const int wm = wid >> 1, wn = wid & 1;
    const int l15 = lane & 15, kg4 = lane >> 4;
    const int n0 = blockIdx.x * 128, m0 = blockIdx.y * 128;

    f32x4 acc[4][4];
#pragma unroll
    for (int i = 0; i < 4; ++i)
#pragma unroll
        for (int j = 0; j < 4; ++j) acc[i][j] = (f32x4)0.f;

    const int r = tid >> 1, hk = tid & 1;

    for (int k0 = 0; k0 < EDIM; k0 += 32) {
        float4 av[4], wv[4];
#pragma unroll
        for (int i = 0; i < 4; ++i) {
            av[i] = *(const float4*)&A[(size_t)(m0 + r) * EDIM + k0 + hk * 16 + i * 4];
            wv[i] = *(const float4*)&W[(size_t)(n0 + r) * EDIM + k0 + hk * 16 + i * 4];
        }
        __syncthreads();
        f16x8 ha0, ha1, hb0, hb1;
#pragma unroll
        for (int i = 0; i < 4; ++i) {
            const float* af = (const float*)&av[i];
            const float* wf = (const float*)&wv[i];
            if (i < 2) {
#pragma unroll
                for (int j = 0; j < 4; ++j) { ha0[i * 4 + j] = (_Float16)af[j]; hb0[i * 4 + j] = (_Float16)wf[j]; }
            } else {
#pragma unroll
                for (int j = 0; j < 4; ++j) { ha1[(i - 2) * 4 + j] = (_Float16)af[j]; hb1[(i - 2) * 4 + j] = (_Float16)wf[j]; }
            }
        }
        *(f16x8*)&As[r][hk * 16] = ha0;
        *(f16x8*)&As[r][hk * 16 + 8] = ha1;
        *(f16x8*)&Bs[r][hk * 16] = hb0;
        *(f16x8*)&Bs[r][hk * 16 + 8] = hb1;
        __syncthreads();

        f16x8 a8[4];
#pragma unroll
        for (int mf = 0; mf < 4; ++mf)
            a8[mf] = *(const f16x8*)&As[wm * 64 + mf * 16 + l15][kg4 * 8];
#pragma unroll
        for (int nf = 0; nf < 4; ++nf) {
            const f16x8 b8 = *(const f16x8*)&Bs[wn * 64 + nf * 16 + l15][kg4 * 8];
#pragma unroll
            for (int mf = 0; mf < 4; ++mf)
                acc[mf][nf] = __builtin_amdgcn_mfma_f32_16x16x32_f16(a8[mf], b8, acc[mf][nf], 0, 0, 0);
        }
    }

#pragma unroll
    for (int nf = 0; nf < 4; ++nf) {
        const int n = n0 + wn * 64 + nf * 16 + l15;
        const float bi = bias[n];
        const float sc = (scale ? scale[n] : 1.f) * smul;
#pragma unroll
        for (int mf = 0; mf < 4; ++mf)
#pragma unroll
            for (int rr = 0; rr < 4; ++rr) {
                const int m = m0 + wm * 64 + mf * 16 + kg4 * 4 + rr;
                C[(size_t)m * EDIM + n] = (_Float16)((acc[mf][nf][rr] + bi) * sc);
            }
    }
}

// ---------------- L1-distance attention, MFMA PV ----------------------------
// grid (NC*2, H, B) = 1024 blocks; block = 4 waves x 32 q, chunk 256 k.
// q staged per-wave in LDS (frees 64 VGPRs -> 4 blocks/CU); dist loop
// c8-outer so q is re-read once per c8 and each K b128 serves 2 q-subtiles.
__device__ __forceinline__ float l1acc(unsigned ku, unsigned qu, float acc) {
    const h2 d = __builtin_bit_cast(h2, ku) - __builtin_bit_cast(h2, qu);
    const unsigned du = __builtin_bit_cast(unsigned, d) & 0x7fff7fffu;
    const h2 one2 = {(_Float16)1.f, (_Float16)1.f};
    return __builtin_amdgcn_fdot2(__builtin_bit_cast(h2, du), one2, acc, false);
}

__global__ __launch_bounds__(256, 4) void attn_mfma_kernel(
    const _Float16* __restrict__ qh, const _Float16* __restrict__ kh,
    const _Float16* __restrict__ vT, const void* __restrict__ mask,
    const float* __restrict__ rel, const int* __restrict__ mflag,
    unsigned short* __restrict__ po, float* __restrict__ ps) {
    __shared__ union SM {
        struct { _Float16 K[64][64]; _Float16 V[64][64]; _Float16 M[64]; } t;
        _Float16 osm[64][136];  // epilogue d x q transpose buffer
    } sm;
    __shared__ f16x8 qsm[4][8][32];  // [wave][c8-unit][q-row]

    const int tid = threadIdx.x;
    const int lane = tid & 63, wid = tid >> 6;
    const int l15 = lane & 15, kg4 = lane >> 4;
    const int row8 = lane >> 3, u = lane & 7;
    const int c = blockIdx.x & (NC - 1), qhi = blockIdx.x / NC;
    const int h = blockIdx.y, b = blockIdx.z;
    const int qbase = qhi * 128 + wid * 32;
    const int mfl = *mflag;
    const float adn = rel[b * NHEAD + h];

    // stage this wave's 32 q rows into its LDS region: [c8][row] 16B units
#pragma unroll
    for (int s = 0; s < 2; ++s) {
        const size_t qrow = (size_t)(b * QLEN + qbase + s * 16 + l15) * EDIM + h * DHEAD;
#pragma unroll
        for (int c8 = 0; c8 < 8; ++c8)
            qsm[wid][c8][s * 16 + l15] = *(const f16x8*)&qh[qrow + c8 * 8];
    }
    // no barrier needed: each wave reads only its own region (lgkmcnt ordered)

    f32x4 acc[2][4];
#pragma unroll
    for (int s = 0; s < 2; ++s)
#pragma unroll
        for (int nf = 0; nf < 4; ++nf) acc[s][nf] = (f32x4)0.f;
    float sacc[2] = {0.f, 0.f};

    const int kc0 = c * (KLEN / NC);
    for (int t = 0; t < (KLEN / NC) / 64; ++t) {
        const int kbase = kc0 + t * 64;
        __syncthreads();  // previous tile fully consumed
        {
            // K: LDS[r][u] <- global unit u^((r>>3)&7)  (read-side row-group XOR)
            // V: LDS[d][u] <- global unit u^(d&7)
#pragma unroll
            for (int i = 0; i < 2; ++i) {
                const int rr = wid * 16 + i * 8 + row8;
                const int swk = (u ^ ((rr >> 3) & 7)) * 8;
                const int swv = (u ^ (rr & 7)) * 8;
                GLDS16(&kh[(size_t)(b * KLEN + kbase + rr) * EDIM + h * DHEAD + swk],
                       &sm.t.K[wid * 16 + i * 8][0]);
                GLDS16(&vT[(size_t)((b * NHEAD + h) * DHEAD + rr) * KLEN + kbase + swv],
                       &sm.t.V[wid * 16 + i * 8][0]);
            }
            if (tid < 64) {
                const int kg = b * KLEN + kbase + tid;
                const int mv = mfl ? ((const int*)mask)[kg]
                                   : (int)((const unsigned char*)mask)[kg];
                sm.t.M[tid] = mv ? (_Float16)1.f : (_Float16)0.f;
            }
        }
        __syncthreads();  // drains glds (vmcnt) + mask writes

        float dist[2][16];
#pragma unroll
        for (int s = 0; s < 2; ++s)
#pragma unroll
            for (int j = 0; j < 16; ++j) dist[s][j] = 0.f;

#pragma unroll
        for (int c8 = 0; c8 < 8; ++c8) {
            u32x4 qv[2];
            qv[0] = __builtin_bit_cast(u32x4, qsm[wid][c8][l15]);
            qv[1] = __builtin_bit_cast(u32x4, qsm[wid][c8][16 + l15]);
#pragma unroll
            for (int hf = 0; hf < 2; ++hf) {
                const int unit = (c8 ^ (hf * 4 + kg4)) * 8;
#pragma unroll
                for (int j = 0; j < 8; ++j) {
                    const int kk = hf * 32 + kg4 * 8 + j;
                    const u32x4 ku =
                        __builtin_bit_cast(u32x4, *(const f16x8*)&sm.t.K[kk][unit]);
#pragma unroll
                    for (int p = 0; p < 4; ++p) {
                        dist[0][hf * 8 + j] = l1acc(ku[p], qv[0][p], dist[0][hf * 8 + j]);
                        dist[1][hf * 8 + j] = l1acc(ku[p], qv[1][p], dist[1][hf * 8 + j]);
                    }
                }
            }
        }

#pragma unroll
        for (int hf = 0; hf < 2; ++hf) {
            const f16x8 mv8 = *(const f16x8*)&sm.t.M[hf * 32 + kg4 * 8];
            unsigned pw[2][4];
#pragma unroll
            for (int s = 0; s < 2; ++s) {
                float w[8];
#pragma unroll
                for (int j = 0; j < 8; ++j) {
                    // e = mask * 2^(C2 - dist); w = e/(e+adn)  (== reference)
                    const float e = exp2f(C2EXP - dist[s][hf * 8 + j]) * (float)mv8[j];
                    w[j] = e * __builtin_amdgcn_rcpf(e + adn);
                    sacc[s] += w[j];
                }
#pragma unroll
                for (int m2 = 0; m2 < 4; ++m2)
                    pw[s][m2] = __builtin_bit_cast(unsigned,
                        __builtin_amdgcn_cvt_pkrtz(w[2 * m2], w[2 * m2 + 1]));
            }
#pragma unroll
            for (int nf = 0; nf < 4; ++nf) {
                const int vrow = nf * 16 + l15;
                const f16x8 b8 = *(const f16x8*)
                    &sm.t.V[vrow][(((hf * 4 + kg4) ^ (l15 & 7))) * 8];
                union { unsigned u[4]; f16x8 v; } a0, a1;
#pragma unroll
                for (int p = 0; p < 4; ++p) { a0.u[p] = pw[0][p]; a1.u[p] = pw[1][p]; }
                acc[0][nf] = __builtin_amdgcn_mfma_f32_16x16x32_f16(a0.v, b8, acc[0][nf], 0, 0, 0);
                acc[1][nf] = __builtin_amdgcn_mfma_f32_16x16x32_f16(a1.v, b8, acc[1][nf], 0, 0, 0);
            }
        }
    }

#pragma unroll
    for (int s = 0; s < 2; ++s) {
        sacc[s] += __shfl_xor(sacc[s], 16);
        sacc[s] += __shfl_xor(sacc[s], 32);
    }
    const size_t bhc = (size_t)(b * NHEAD + h) * NC + c;
    if (lane < 16) {
#pragma unroll
        for (int s = 0; s < 2; ++s)
            ps[bhc * QLEN + qbase + s * 16 + lane] = sacc[s];
    }

    __syncthreads();  // everyone done with sm.t
#pragma unroll
    for (int s = 0; s < 2; ++s)
#pragma unroll
        for (int nf = 0; nf < 4; ++nf)
#pragma unroll
            for (int rr = 0; rr < 4; ++rr) {
                const int qloc = wid * 32 + s * 16 + kg4 * 4 + rr;
                sm.osm[nf * 16 + l15][qloc] = (_Float16)acc[s][nf][rr];
            }
    __syncthreads();
    {
        const int d = tid >> 2, seg = tid & 3;
        const f16x8* src = (const f16x8*)&sm.osm[d][seg * 32];
        f16x8* dst = (f16x8*)(po + (bhc * 64 + d) * QLEN + qhi * 128 + seg * 32);
#pragma unroll
        for (int i = 0; i < 4; ++i) dst[i] = src[i];
    }
}

// ---------------- combine partials, normalize, write out --------------------
__global__ __launch_bounds__(256) void combine_kernel(
    const unsigned short* __restrict__ po, const float* __restrict__ ps,
    float* __restrict__ out, int nch) {
    const int d4 = blockIdx.x, h = blockIdx.y, b = blockIdx.z;
    const int q = threadIdx.x;
    const int bh = b * NHEAD + h;

    float s = 0.f;
    for (int c = 0; c < nch; ++c)
        s += ps[((size_t)(bh * nch + c)) * QLEN + q];

    float o[4] = {0.f, 0.f, 0.f, 0.f};
    for (int c = 0; c < nch; ++c) {
#pragma unroll
        for (int j = 0; j < 4; ++j) {
            const int d = d4 * 4 + j;
            const unsigned short raw = po[((size_t)((bh * nch + c) * 64 + d)) * QLEN + q];
            o[j] += (float)*(const _Float16*)&raw;
        }
    }
    const float inv = 1.0f / fmaxf(s, 1e-12f);
#pragma unroll
    for (int j = 0; j < 4; ++j)
        out[((size_t)(b * QLEN + q)) * EDIM + h * DHEAD + d4 * 4 + j] = o[j] * inv;
}

extern "C" void kernel_launch(void* const* d_in, const int* in_sizes, int n_in,
                              void* d_out, int out_size, void* d_ws, size_t ws_size,
                              hipStream_t stream) {
    const float* query = (const float*)d_in[0];
    const float* bag   = (const float*)d_in[1];
    const void*  mask  = d_in[2];
    const float* rel   = (const float*)d_in[3];
    const float* Wqk   = (const float*)d_in[4];
    const float* bqk   = (const float*)d_in[5];
    const float* Wv    = (const float*)d_in[6];
    const float* bv    = (const float*)d_in[7];
    const float* diag  = (const float*)d_in[8];  // [H*DH] == q/k column order
    float* out = (float*)d_out;

    char* wsb = (char*)d_ws;
    int* mflag = (int*)wsb;
    _Float16* qh = (_Float16*)(wsb + 16);
    _Float16* kh = qh + (size_t)BATCH * QLEN * EDIM;
    _Float16* vT = kh + (size_t)BATCH * KLEN * EDIM;
    char* region = (char*)(vT + (size_t)BATCH * KLEN * EDIM);
    // phase 1 (pre-attn)
    _Float16* bag_h = (_Float16*)region;
    _Float16* wqk_h = bag_h + (size_t)BATCH * KLEN * EDIM;
    _Float16* wv_h = wqk_h + (size_t)EDIM * EDIM;
    // phase 2 (attn output partials) — overlaps phase 1 (order-safe)
    unsigned short* po = (unsigned short*)region;
    float* psb = (float*)(region + (size_t)BATCH * NHEAD * NC * QLEN * DHEAD * 2);

    detect_mask_kernel<<<1, 256, 0, stream>>>((const unsigned char*)mask, mflag);

    convert_kernel<<<2048, 256, 0, stream>>>(bag, Wqk, Wv, bag_h, wqk_h, wv_h);

    // q' = (query@Wqk^T + bqk) * diag * alpha  (mixed path, small)
    gemm_f16_mfma<<<dim3(EDIM / 128, (BATCH * QLEN) / 128), 256, 0, stream>>>(
        query, Wqk, bqk, diag, ALPHA, qh);
    // k' = (bag@Wqk^T + bqk) * diag * alpha
    gemm_h16_mfma<0><<<dim3(EDIM / 64, (BATCH * KLEN) / 64), 256, 0, stream>>>(
        bag_h, wqk_h, bqk, diag, ALPHA, kh);
    // v = bag@Wv^T + bv  -> transposed vT
    gemm_h16_mfma<1><<<dim3(EDIM / 64, (BATCH * KLEN) / 64), 256, 0, stream>>>(
        bag_h, wv_h, bv, nullptr, 1.f, vT);

    attn_mfma_kernel<<<dim3(NC * 2, NHEAD, BATCH), 256, 0, stream>>>(
        qh, kh, vT, mask, rel, mflag, po, psb);

    combine_kernel<<<dim3(16, NHEAD, BATCH), 256, 0, stream>>>(po, psb, out, NC);
}

// Round 6
// 167.478 us; speedup vs baseline: 1.4999x; 1.4999x over previous
//
#include <hip/hip_runtime.h>

// CAPBlock r6: v_sad_u16 L1 distance on u16-quantized q/k (1 op per 2 dims,
// accumulate included), r4 128^2-tile GEMMs restored with quantizing epilogues.
// Shapes: B=4, Q=256, K=4096, Ein=E=512, H=8, DH=64.
//
// ws (52.43MB):
//   mflag 16B | qh u16 1MB | kh u16 16.8MB | vT f16 16.8MB | REGION 17.8MB
//   REGION phase1: bag_h 16.8 | wqk_h 0.5 | wv_h 0.5   (convert -> GEMMs)
//   REGION phase2: po 16.8 | ps 0.5                     (attn -> combine)

#define BATCH 4
#define QLEN 256
#define KLEN 4096
#define EDIM 512
#define NHEAD 8
#define DHEAD 64
#define NC 16

// alpha = log2(e)/L1_SCALING ; C2 = L1_CENTER*alpha  (k,q prescaled by alpha)
#define ALPHA 0.21153831f
#define C2EXP 15.276518f
// u16 quantization: value*16384 + 32768 (covers +-2.0 = 9.5 sigma post-fold)
#define QSCALE 16384.0f
#define SADSCALE 6.103515625e-5f  // 1/16384

typedef float f32x4 __attribute__((ext_vector_type(4)));
typedef _Float16 f16x8 __attribute__((ext_vector_type(8)));
typedef _Float16 f16x4 __attribute__((ext_vector_type(4)));
typedef unsigned int u32x4 __attribute__((ext_vector_type(4)));

// async global->LDS 16B: dest = uniform base + lane*16; source per-lane.
#define GLDS16(g, l)                                                     \
    __builtin_amdgcn_global_load_lds(                                    \
        (const __attribute__((address_space(1))) unsigned int*)(g),      \
        (__attribute__((address_space(3))) unsigned int*)(l), 16, 0, 0)

__device__ __forceinline__ unsigned short quant_u16(float x) {
    // round-half-up of x*QSCALE + 32768, clamped to [0, 65535]
    const float y = fminf(fmaxf(x * QSCALE + 32768.5f, 0.f), 65535.f);
    return (unsigned short)y;
}

// ---------------- mask dtype detection (bool-as-byte vs int32) --------------
__global__ void detect_mask_kernel(const unsigned char* __restrict__ m,
                                   int* __restrict__ flag) {
    __shared__ int nz;
    if (threadIdx.x == 0) nz = 0;
    __syncthreads();
    int acc = 0;
    for (int i = threadIdx.x; i < BATCH * KLEN; i += 256)
        if (i & 3) acc |= m[i];
    if (acc) atomicOr(&nz, 1);
    __syncthreads();
    if (threadIdx.x == 0) *flag = (nz == 0) ? 1 : 0;  // 1 => int32, 0 => byte
}

// ---------------- f32 -> fp16 convert (bag, Wqk, Wv) ------------------------
__global__ __launch_bounds__(256) void convert_kernel(
    const float* __restrict__ bag, const float* __restrict__ wqk,
    const float* __restrict__ wv, _Float16* __restrict__ bag_h,
    _Float16* __restrict__ wqk_h, _Float16* __restrict__ wv_h) {
    const int NB = (BATCH * KLEN * EDIM) / 4;  // float4 counts
    const int NW = (EDIM * EDIM) / 4;
    for (int i = blockIdx.x * 256 + threadIdx.x; i < NB + 2 * NW;
         i += gridDim.x * 256) {
        const float4* s;
        _Float16* d;
        int j;
        if (i < NB) { s = (const float4*)bag; d = bag_h; j = i; }
        else if (i < NB + NW) { s = (const float4*)wqk; d = wqk_h; j = i - NB; }
        else { s = (const float4*)wv; d = wv_h; j = i - NB - NW; }
        const float4 v = s[j];
        f16x4 h;
        h[0] = (_Float16)v.x; h[1] = (_Float16)v.y;
        h[2] = (_Float16)v.z; h[3] = (_Float16)v.w;
        *(f16x4*)&d[(size_t)j * 4] = h;
    }
}

// ---------------- pure-fp16 NT MFMA GEMM, 128x128 tile (r4 variant) ---------
// C[m][n] = sum_k A[m][k]*W[n][k]; BK=64, 4 waves (2x2), wave 64x64 = 4x4
// frags of 16x16x32. Register staging + LDS unit-XOR swizzle u^(row&7).
// OUTM=0: u16-quantized out, quant((acc+bias[n])*scale[n]*smul).
// OUTM=1: vT[(b*8+h)*64+d][k] fp16, acc+bias[n].
template <int OUTM>
__global__ __launch_bounds__(256) void gemm_h16_mfma(
    const _Float16* __restrict__ A, const _Float16* __restrict__ W,
    const float* __restrict__ bias, const float* __restrict__ scale,
    float smul, void* __restrict__ Cout) {
    __shared__ _Float16 Ah[128][64];
    __shared__ _Float16 Bh[128][64];

    const int tid = threadIdx.x;
    const int lane = tid & 63, wid = tid >> 6;
    const int wm = wid >> 1, wn = wid & 1;
    const int l15 = lane & 15, kg4 = lane >> 4;
    const int n0 = blockIdx.x * 128, m0 = blockIdx.y * 128;

    f32x4 acc[4][4];
#pragma unroll
    for (int i = 0; i < 4; ++i)
#pragma unroll
        for (int j = 0; j < 4; ++j) acc[i][j] = (f32x4)0.f;

    for (int k0 = 0; k0 < EDIM; k0 += 64) {
        f16x8 av[4], wv[4];
        int rowv[4], uv[4];
#pragma unroll
        for (int i = 0; i < 4; ++i) {  // lane-contiguous 16B: coalesced 1KB/wave
            const int idx = i * 256 + tid;
            rowv[i] = idx >> 3;
            uv[i] = idx & 7;
            av[i] = *(const f16x8*)&A[(size_t)(m0 + rowv[i]) * EDIM + k0 + uv[i] * 8];
            wv[i] = *(const f16x8*)&W[(size_t)(n0 + rowv[i]) * EDIM + k0 + uv[i] * 8];
        }
        __syncthreads();  // previous tile consumed
#pragma unroll
        for (int i = 0; i < 4; ++i) {
            const int sw = (uv[i] ^ (rowv[i] & 7)) * 8;
            *(f16x8*)&Ah[rowv[i]][sw] = av[i];
            *(f16x8*)&Bh[rowv[i]][sw] = wv[i];
        }
        __syncthreads();

#pragma unroll
        for (int s = 0; s < 2; ++s) {
            f16x8 a8[4], b8[4];
#pragma unroll
            for (int mf = 0; mf < 4; ++mf) {
                const int row = wm * 64 + mf * 16 + l15;
                a8[mf] = *(const f16x8*)&Ah[row][((s * 4 + kg4) ^ (row & 7)) * 8];
            }
#pragma unroll
            for (int nf = 0; nf < 4; ++nf) {
                const int row = wn * 64 + nf * 16 + l15;
                b8[nf] = *(const f16x8*)&Bh[row][((s * 4 + kg4) ^ (row & 7)) * 8];
            }
#pragma unroll
            for (int nf = 0; nf < 4; ++nf)
#pragma unroll
                for (int mf = 0; mf < 4; ++mf)
                    acc[mf][nf] = __builtin_amdgcn_mfma_f32_16x16x32_f16(
                        a8[mf], b8[nf], acc[mf][nf], 0, 0, 0);
        }
    }

#pragma unroll
    for (int nf = 0; nf < 4; ++nf) {
        const int n = n0 + wn * 64 + nf * 16 + l15;
        const float bi = bias[n];
        if constexpr (OUTM == 0) {
            const float sc = (scale ? scale[n] : 1.f) * smul;
            unsigned short* C = (unsigned short*)Cout;
#pragma unroll
            for (int mf = 0; mf < 4; ++mf)
#pragma unroll
                for (int rr = 0; rr < 4; ++rr) {
                    const int m = m0 + wm * 64 + mf * 16 + kg4 * 4 + rr;
                    C[(size_t)m * EDIM + n] = quant_u16((acc[mf][nf][rr] + bi) * sc);
                }
        } else {
            _Float16* C = (_Float16*)Cout;
#pragma unroll
            for (int mf = 0; mf < 4; ++mf) {
                const int kb = m0 + wm * 64 + mf * 16 + kg4 * 4;  // global m
                const int bb = kb >> 12, kk = kb & (KLEN - 1);    // batch, k
                f16x4 pk;
#pragma unroll
                for (int rr = 0; rr < 4; ++rr) pk[rr] = (_Float16)(acc[mf][nf][rr] + bi);
                *(f16x4*)&C[((size_t)(bb * NHEAD + (n >> 6)) * DHEAD + (n & 63)) * KLEN + kk] = pk;
            }
        }
    }
}

// ---------------- mixed f32->fp16 MFMA GEMM (query projection, small) -------
__global__ __launch_bounds__(256) void gemm_f16_mfma(
    const float* __restrict__ A, const float* __restrict__ W,
    const float* __restrict__ bias, const float* __restrict__ scale,
    float smul, unsigned short* __restrict__ C) {
    __shared__ _Float16 As[128][40];
    __shared__ _Float16 Bs[128][40];

    const int tid = threadIdx.x;
    const int lane = tid & 63, wid = tid >> 6;
    const int wm = wid >> 1, wn = wid & 1;
    const int l15 = lane & 15, kg4 = lane >> 4;
    const int n0 = blockIdx.x * 128, m0 = blockIdx.y * 128;

    f32x4 acc[4][4];
#pragma unroll
    for (int i = 0; i < 4; ++i)
#pragma unroll
        for (int j = 0; j < 4; ++j) acc[i][j] = (f32x4)0.f;

    const int r = tid >> 1, hk = tid & 1;

    for (int k0 = 0; k0 < EDIM; k0 += 32) {
        float4 av[4], wv[4];
#pragma unroll
        for (int i = 0; i < 4; ++i) {
            av[i] = *(const float4*)&A[(size_t)(m0 + r) * EDIM + k0 + hk * 16 + i * 4];
            wv[i] = *(const float4*)&W[(size_t)(n0 + r) * EDIM + k0 + hk * 16 + i * 4];
        }
        __syncthreads();
        f16x8 ha0, ha1, hb0, hb1;
#pragma unroll
        for (int i = 0; i < 4; ++i) {
            const float* af = (const float*)&av[i];
            const float* wf = (const float*)&wv[i];
            if (i < 2) {
#pragma unroll
                for (int j = 0; j < 4; ++j) { ha0[i * 4 + j] = (_Float16)af[j]; hb0[i * 4 + j] = (_Float16)wf[j]; }
            } else {
#pragma unroll
                for (int j = 0; j < 4; ++j) { ha1[(i - 2) * 4 + j] = (_Float16)af[j]; hb1[(i - 2) * 4 + j] = (_Float16)wf[j]; }
            }
        }
        *(f16x8*)&As[r][hk * 16] = ha0;
        *(f16x8*)&As[r][hk * 16 + 8] = ha1;
        *(f16x8*)&Bs[r][hk * 16] = hb0;
        *(f16x8*)&Bs[r][hk * 16 + 8] = hb1;
        __syncthreads();

        f16x8 a8[4];
#pragma unroll
        for (int mf = 0; mf < 4; ++mf)
            a8[mf] = *(const f16x8*)&As[wm * 64 + mf * 16 + l15][kg4 * 8];
#pragma unroll
        for (int nf = 0; nf < 4; ++nf) {
            const f16x8 b8 = *(const f16x8*)&Bs[wn * 64 + nf * 16 + l15][kg4 * 8];
#pragma unroll
            for (int mf = 0; mf < 4; ++mf)
                acc[mf][nf] = __builtin_amdgcn_mfma_f32_16x16x32_f16(a8[mf], b8, acc[mf][nf], 0, 0, 0);
        }
    }

#pragma unroll
    for (int nf = 0; nf < 4; ++nf) {
        const int n = n0 + wn * 64 + nf * 16 + l15;
        const float bi = bias[n];
        const float sc = (scale ? scale[n] : 1.f) * smul;
#pragma unroll
        for (int mf = 0; mf < 4; ++mf)
#pragma unroll
            for (int rr = 0; rr < 4; ++rr) {
                const int m = m0 + wm * 64 + mf * 16 + kg4 * 4 + rr;
                C[(size_t)m * EDIM + n] = quant_u16((acc[mf][nf][rr] + bi) * sc);
            }
    }
}

// ---------------- L1-distance attention: v_sad_u16 + MFMA PV ----------------
// grid (NC*2, H, B) = 1024 blocks; block = 4 waves x 32 q, chunk 256 k.
// q staged per-wave in LDS; dist accumulates in u32 via sad_u16 (2 dims/op).
__global__ __launch_bounds__(256, 4) void attn_mfma_kernel(
    const unsigned short* __restrict__ qh, const unsigned short* __restrict__ kh,
    const _Float16* __restrict__ vT, const void* __restrict__ mask,
    const float* __restrict__ rel, const int* __restrict__ mflag,
    unsigned short* __restrict__ po, float* __restrict__ ps) {
    __shared__ union SM {
        struct { unsigned short K[64][64]; _Float16 V[64][64]; _Float16 M[64]; } t;
        _Float16 osm[64][136];  // epilogue d x q transpose buffer
    } sm;
    __shared__ u32x4 qsm[4][8][32];  // [wave][c8-unit][q-row], u16 data

    const int tid = threadIdx.x;
    const int lane = tid & 63, wid = tid >> 6;
    const int l15 = lane & 15, kg4 = lane >> 4;
    const int row8 = lane >> 3, u = lane & 7;
    const int c = blockIdx.x & (NC - 1), qhi = blockIdx.x / NC;
    const int h = blockIdx.y, b = blockIdx.z;
    const int qbase = qhi * 128 + wid * 32;
    const int mfl = *mflag;
    const float adn = rel[b * NHEAD + h];

    // stage this wave's 32 q rows into its LDS region: [c8][row] 16B units
#pragma unroll
    for (int s = 0; s < 2; ++s) {
        const size_t qrow = (size_t)(b * QLEN + qbase + s * 16 + l15) * EDIM + h * DHEAD;
#pragma unroll
        for (int c8 = 0; c8 < 8; ++c8)
            qsm[wid][c8][s * 16 + l15] = *(const u32x4*)&qh[qrow + c8 * 8];
    }
    // no barrier needed: each wave reads only its own region (lgkmcnt ordered)

    f32x4 acc[2][4];
#pragma unroll
    for (int s = 0; s < 2; ++s)
#pragma unroll
        for (int nf = 0; nf < 4; ++nf) acc[s][nf] = (f32x4)0.f;
    float sacc[2] = {0.f, 0.f};

    const int kc0 = c * (KLEN / NC);
    for (int t = 0; t < (KLEN / NC) / 64; ++t) {
        const int kbase = kc0 + t * 64;
        __syncthreads();  // previous tile fully consumed
        {
            // K: LDS[r][u] <- global unit u^((r>>3)&7)  (read-side row-group XOR)
            // V: LDS[d][u] <- global unit u^(d&7)
#pragma unroll
            for (int i = 0; i < 2; ++i) {
                const int rr = wid * 16 + i * 8 + row8;
                const int swk = (u ^ ((rr >> 3) & 7)) * 8;
                const int swv = (u ^ (rr & 7)) * 8;
                GLDS16(&kh[(size_t)(b * KLEN + kbase + rr) * EDIM + h * DHEAD + swk],
                       &sm.t.K[wid * 16 + i * 8][0]);
                GLDS16(&vT[(size_t)((b * NHEAD + h) * DHEAD + rr) * KLEN + kbase + swv],
                       &sm.t.V[wid * 16 + i * 8][0]);
            }
            if (tid < 64) {
                const int kg = b * KLEN + kbase + tid;
                const int mv = mfl ? ((const int*)mask)[kg]
                                   : (int)((const unsigned char*)mask)[kg];
                sm.t.M[tid] = mv ? (_Float16)1.f : (_Float16)0.f;
            }
        }
        __syncthreads();  // drains glds (vmcnt) + mask writes

        unsigned dist[2][16];
#pragma unroll
        for (int s = 0; s < 2; ++s)
#pragma unroll
            for (int j = 0; j < 16; ++j) dist[s][j] = 0u;

#pragma unroll
        for (int c8 = 0; c8 < 8; ++c8) {
            u32x4 qv[2];
            qv[0] = qsm[wid][c8][l15];
            qv[1] = qsm[wid][c8][16 + l15];
#pragma unroll
            for (int hf = 0; hf < 2; ++hf) {
                const int unit = (c8 ^ (hf * 4 + kg4)) * 8;
#pragma unroll
                for (int j = 0; j < 8; ++j) {
                    const int kk = hf * 32 + kg4 * 8 + j;
                    const u32x4 ku = *(const u32x4*)&sm.t.K[kk][unit];
#pragma unroll
                    for (int p = 0; p < 4; ++p) {
                        // 2 dims of L1 distance + accumulate, one instruction
                        dist[0][hf * 8 + j] =
                            __builtin_amdgcn_sad_u16(ku[p], qv[0][p], dist[0][hf * 8 + j]);
                        dist[1][hf * 8 + j] =
                            __builtin_amdgcn_sad_u16(ku[p], qv[1][p], dist[1][hf * 8 + j]);
                    }
                }
            }
        }

#pragma unroll
        for (int hf = 0; hf < 2; ++hf) {
            const f16x8 mv8 = *(const f16x8*)&sm.t.M[hf * 32 + kg4 * 8];
            unsigned pw[2][4];
#pragma unroll
            for (int s = 0; s < 2; ++s) {
                float w[8];
#pragma unroll
                for (int j = 0; j < 8; ++j) {
                    // e = mask * 2^(C2 - dist*s); w = e/(e+adn)  (== reference)
                    const float e =
                        exp2f(C2EXP - (float)dist[s][hf * 8 + j] * SADSCALE) * (float)mv8[j];
                    w[j] = e * __builtin_amdgcn_rcpf(e + adn);
                    sacc[s] += w[j];
                }
#pragma unroll
                for (int m2 = 0; m2 < 4; ++m2)
                    pw[s][m2] = __builtin_bit_cast(unsigned,
                        __builtin_amdgcn_cvt_pkrtz(w[2 * m2], w[2 * m2 + 1]));
            }
#pragma unroll
            for (int nf = 0; nf < 4; ++nf) {
                const int vrow = nf * 16 + l15;
                const f16x8 b8 = *(const f16x8*)
                    &sm.t.V[vrow][(((hf * 4 + kg4) ^ (l15 & 7))) * 8];
                union { unsigned u[4]; f16x8 v; } a0, a1;
#pragma unroll
                for (int p = 0; p < 4; ++p) { a0.u[p] = pw[0][p]; a1.u[p] = pw[1][p]; }
                acc[0][nf] = __builtin_amdgcn_mfma_f32_16x16x32_f16(a0.v, b8, acc[0][nf], 0, 0, 0);
                acc[1][nf] = __builtin_amdgcn_mfma_f32_16x16x32_f16(a1.v, b8, acc[1][nf], 0, 0, 0);
            }
        }
    }

#pragma unroll
    for (int s = 0; s < 2; ++s) {
        sacc[s] += __shfl_xor(sacc[s], 16);
        sacc[s] += __shfl_xor(sacc[s], 32);
    }
    const size_t bhc = (size_t)(b * NHEAD + h) * NC + c;
    if (lane < 16) {
#pragma unroll
        for (int s = 0; s < 2; ++s)
            ps[bhc * QLEN + qbase + s * 16 + lane] = sacc[s];
    }

    __syncthreads();  // everyone done with sm.t
#pragma unroll
    for (int s = 0; s < 2; ++s)
#pragma unroll
        for (int nf = 0; nf < 4; ++nf)
#pragma unroll
            for (int rr = 0; rr < 4; ++rr) {
                const int qloc = wid * 32 + s * 16 + kg4 * 4 + rr;
                sm.osm[nf * 16 + l15][qloc] = (_Float16)acc[s][nf][rr];
            }
    __syncthreads();
    {
        const int d = tid >> 2, seg = tid & 3;
        const f16x8* src = (const f16x8*)&sm.osm[d][seg * 32];
        f16x8* dst = (f16x8*)(po + (bhc * 64 + d) * QLEN + qhi * 128 + seg * 32);
#pragma unroll
        for (int i = 0; i < 4; ++i) dst[i] = src[i];
    }
}

// ---------------- combine partials, normalize, write out --------------------
__global__ __launch_bounds__(256) void combine_kernel(
    const unsigned short* __restrict__ po, const float* __restrict__ ps,
    float* __restrict__ out, int nch) {
    const int d4 = blockIdx.x, h = blockIdx.y, b = blockIdx.z;
    const int q = threadIdx.x;
    const int bh = b * NHEAD + h;

    float s = 0.f;
    for (int c = 0; c < nch; ++c)
        s += ps[((size_t)(bh * nch + c)) * QLEN + q];

    float o[4] = {0.f, 0.f, 0.f, 0.f};
    for (int c = 0; c < nch; ++c) {
#pragma unroll
        for (int j = 0; j < 4; ++j) {
            const int d = d4 * 4 + j;
            const unsigned short raw = po[((size_t)((bh * nch + c) * 64 + d)) * QLEN + q];
            o[j] += (float)*(const _Float16*)&raw;
        }
    }
    const float inv = 1.0f / fmaxf(s, 1e-12f);
#pragma unroll
    for (int j = 0; j < 4; ++j)
        out[((size_t)(b * QLEN + q)) * EDIM + h * DHEAD + d4 * 4 + j] = o[j] * inv;
}

extern "C" void kernel_launch(void* const* d_in, const int* in_sizes, int n_in,
                              void* d_out, int out_size, void* d_ws, size_t ws_size,
                              hipStream_t stream) {
    const float* query = (const float*)d_in[0];
    const float* bag   = (const float*)d_in[1];
    const void*  mask  = d_in[2];
    const float* rel   = (const float*)d_in[3];
    const float* Wqk   = (const float*)d_in[4];
    const float* bqk   = (const float*)d_in[5];
    const float* Wv    = (const float*)d_in[6];
    const float* bv    = (const float*)d_in[7];
    const float* diag  = (const float*)d_in[8];  // [H*DH] == q/k column order
    float* out = (float*)d_out;

    char* wsb = (char*)d_ws;
    int* mflag = (int*)wsb;
    unsigned short* qh = (unsigned short*)(wsb + 16);
    unsigned short* kh = qh + (size_t)BATCH * QLEN * EDIM;
    _Float16* vT = (_Float16*)(kh + (size_t)BATCH * KLEN * EDIM);
    char* region = (char*)(vT + (size_t)BATCH * KLEN * EDIM);
    // phase 1 (pre-attn)
    _Float16* bag_h = (_Float16*)region;
    _Float16* wqk_h = bag_h + (size_t)BATCH * KLEN * EDIM;
    _Float16* wv_h = wqk_h + (size_t)EDIM * EDIM;
    // phase 2 (attn output partials) — overlaps phase 1 (order-safe)
    unsigned short* po = (unsigned short*)region;
    float* psb = (float*)(region + (size_t)BATCH * NHEAD * NC * QLEN * DHEAD * 2);

    detect_mask_kernel<<<1, 256, 0, stream>>>((const unsigned char*)mask, mflag);

    convert_kernel<<<2048, 256, 0, stream>>>(bag, Wqk, Wv, bag_h, wqk_h, wv_h);

    // q' = quant_u16((query@Wqk^T + bqk) * diag * alpha)
    gemm_f16_mfma<<<dim3(EDIM / 128, (BATCH * QLEN) / 128), 256, 0, stream>>>(
        query, Wqk, bqk, diag, ALPHA, qh);
    // k' = quant_u16((bag@Wqk^T + bqk) * diag * alpha)
    gemm_h16_mfma<0><<<dim3(EDIM / 128, (BATCH * KLEN) / 128), 256, 0, stream>>>(
        bag_h, wqk_h, bqk, diag, ALPHA, kh);
    // v = bag@Wv^T + bv  -> transposed vT (fp16)
    gemm_h16_mfma<1><<<dim3(EDIM / 128, (BATCH * KLEN) / 128), 256, 0, stream>>>(
        bag_h, wv_h, bv, nullptr, 1.f, vT);

    attn_mfma_kernel<<<dim3(NC * 2, NHEAD, BATCH), 256, 0, stream>>>(
        qh, kh, vT, mask, rel, mflag, po, psb);

    combine_kernel<<<dim3(16, NHEAD, BATCH), 256, 0, stream>>>(po, psb, out, NC);
}